// Round 4
// baseline (88.675 us; speedup 1.0000x reference)
//
#include <hip/hip_runtime.h>
#include <hip/hip_cooperative_groups.h>

#define MARGIN 0.1f
#define NBEST 64

namespace cg = cooperative_groups;

// One wave processes 4 rows, fully in registers. Column-c broadcast via
// v_readlane (unrolled constant lane) -> SGPR, no LDS, no barrier.
// coop=1: grid.sync() then block 0 reduces partials into out.
// coop=0: skip; a separate reduce kernel finishes.
__global__ __launch_bounds__(256)
void sml_coop(const float* __restrict__ scores,
              const unsigned int* __restrict__ wr32,
              float* __restrict__ ws, float* __restrict__ out,
              int B, int coop)
{
    const int lane = threadIdx.x & 63;
    const int wib  = threadIdx.x >> 6;            // wave-in-block 0..3
    const int b0   = (blockIdx.x * 4 + wib) * 4;  // first of this wave's 4 rows

    // werRank width probe (int64 vs int32), wave-uniform: int64 values in
    // [0,64) -> every odd int32 word is 0.
    unsigned int probe = wr32[2 * lane + 1];
    const bool is64 = (__all(probe == 0u) != 0);

    // Gather: lane owns column i=lane of each of its 4 rows.
    float gv[4];
    #pragma unroll
    for (int r = 0; r < 4; ++r) {
        int b  = b0 + r;
        int bc = (b < B) ? b : (B - 1);
        int idx = bc * NBEST + lane;
        unsigned int rk = is64 ? wr32[2 * idx] : wr32[idx];
        gv[r] = scores[bc * NBEST + (int)(rk & (NBEST - 1))];
    }
    const float tx = MARGIN - gv[0], ty = MARGIN - gv[1];
    const float tz = MARGIN - gv[2], tw = MARGIN - gv[3];

    // acc_r[lane] = sum_{c>lane} max(g_r[c] + t_r, 0)
    // g_r[c] broadcast from lane c via readlane (SGPR, VALU pipe only).
    float a0 = 0.0f, a1 = 0.0f, a2 = 0.0f, a3 = 0.0f;
    #pragma unroll
    for (int c = 1; c < NBEST; ++c) {
        float s0 = __uint_as_float(__builtin_amdgcn_readlane(__float_as_uint(gv[0]), c));
        float s1 = __uint_as_float(__builtin_amdgcn_readlane(__float_as_uint(gv[1]), c));
        float s2 = __uint_as_float(__builtin_amdgcn_readlane(__float_as_uint(gv[2]), c));
        float s3 = __uint_as_float(__builtin_amdgcn_readlane(__float_as_uint(gv[3]), c));
        float m01 = (lane < c) ? 1.0f : 0.0f;     // shared mask, 2 ops
        a0 += fmaxf(s0 + tx, 0.0f) * m01;
        a1 += fmaxf(s1 + ty, 0.0f) * m01;
        a2 += fmaxf(s2 + tz, 0.0f) * m01;
        a3 += fmaxf(s3 + tw, 0.0f) * m01;
    }

    if (b0 + 1 >= B) a1 = 0.0f;                   // tail guards (no-op at B=16384)
    if (b0 + 2 >= B) a2 = 0.0f;
    if (b0 + 3 >= B) a3 = 0.0f;
    if (b0 >= B)     a0 = 0.0f;

    int cnt = (NBEST - 1) - lane;                 // mean denom; lane 63 acc==0
    float acc = (a0 + a1 + a2 + a3) / (float)(cnt > 0 ? cnt : 1);

    #pragma unroll
    for (int off = 32; off > 0; off >>= 1)
        acc += __shfl_down(acc, off);

    __shared__ float wsum[4];
    if (lane == 0) wsum[wib] = acc;
    __syncthreads();
    if (threadIdx.x == 0) {
        ws[blockIdx.x] = wsum[0] + wsum[1] + wsum[2] + wsum[3];
        __threadfence();                          // device-scope visibility (XCDs)
    }

    if (coop) {
        cg::this_grid().sync();
        if (blockIdx.x == 0) {
            const int n = gridDim.x;
            float s = 0.0f;
            for (int i = threadIdx.x; i < n; i += 256) s += ws[i];
            #pragma unroll
            for (int off = 32; off > 0; off >>= 1)
                s += __shfl_down(s, off);
            __shared__ float w2[4];
            if (lane == 0) w2[wib] = s;
            __syncthreads();
            if (threadIdx.x == 0)
                out[0] = w2[0] + w2[1] + w2[2] + w2[3];
        }
    }
}

// Fallback finisher (non-cooperative path only).
__global__ __launch_bounds__(256)
void sml_reduce(const float* __restrict__ ws, float* __restrict__ out, int n)
{
    const int lane = threadIdx.x & 63;
    const int wid  = threadIdx.x >> 6;
    float s = 0.0f;
    for (int i = threadIdx.x; i < n; i += 256) s += ws[i];
    #pragma unroll
    for (int off = 32; off > 0; off >>= 1)
        s += __shfl_down(s, off);
    __shared__ float wsum[4];
    if (lane == 0) wsum[wid] = s;
    __syncthreads();
    if (threadIdx.x == 0)
        out[0] = wsum[0] + wsum[1] + wsum[2] + wsum[3];
}

extern "C" void kernel_launch(void* const* d_in, const int* in_sizes, int n_in,
                              void* d_out, int out_size, void* d_ws, size_t ws_size,
                              hipStream_t stream)
{
    const float* scores    = (const float*)d_in[0];
    const unsigned int* wr = (const unsigned int*)d_in[1];
    float* ws  = (float*)d_ws;
    float* out = (float*)d_out;
    int B = in_sizes[0] / NBEST;

    int blocks = (B + 15) / 16;                   // 16 rows per block
    // Cooperative path requires co-residency: 256-thread blocks -> <=2048.
    bool try_coop = (blocks <= 2048);
    hipError_t err = hipErrorUnknown;
    if (try_coop) {
        int coop = 1;
        void* args[] = { (void*)&scores, (void*)&wr, (void*)&ws,
                         (void*)&out, (void*)&B, (void*)&coop };
        err = hipLaunchCooperativeKernel((const void*)sml_coop,
                                         dim3(blocks), dim3(256),
                                         args, 0, stream);
    }
    if (err != hipSuccess) {
        // Fallback: plain launch (coop=0) + separate reduce kernel.
        sml_coop<<<blocks, 256, 0, stream>>>(scores, wr, ws, out, B, 0);
        sml_reduce<<<1, 256, 0, stream>>>(ws, out, blocks);
    }
}

// Round 5
// 16.118 us; speedup vs baseline: 5.5016x; 5.5016x over previous
//
#include <hip/hip_runtime.h>

#define MARGIN 0.1f
#define NBEST 64
#define ROWS_PER_WAVE 8

// One wave processes 8 rows, fully in registers. Column-c value of row r is
// broadcast from lane c via v_readlane (constant lane index -> SGPR), so the
// inner loop is pure VALU: no LDS reads, no barriers, no atomics.
__global__ __launch_bounds__(256)
void sml_kernel(const float* __restrict__ scores,
                const unsigned int* __restrict__ wr32,
                float* __restrict__ ws, int B)
{
    const int lane = threadIdx.x & 63;
    const int wib  = threadIdx.x >> 6;                       // wave-in-block 0..3
    const int b0   = (blockIdx.x * 4 + wib) * ROWS_PER_WAVE; // first row of wave

    // werRank width probe (int64 vs int32), wave-uniform: int64 values in
    // [0,64) -> every odd int32 word is 0.
    unsigned int probe = wr32[2 * lane + 1];
    const bool is64 = (__all(probe == 0u) != 0);

    // Issue all 8 rank loads, then all 8 score gathers (ILP latency hiding).
    unsigned int rk[ROWS_PER_WAVE];
    #pragma unroll
    for (int r = 0; r < ROWS_PER_WAVE; ++r) {
        int bc = min(b0 + r, B - 1);
        int idx = bc * NBEST + lane;
        rk[r] = is64 ? wr32[2 * idx] : wr32[idx];
    }
    float gv[ROWS_PER_WAVE];
    #pragma unroll
    for (int r = 0; r < ROWS_PER_WAVE; ++r) {
        int bc = min(b0 + r, B - 1);
        gv[r] = scores[bc * NBEST + (int)(rk[r] & (NBEST - 1))];
    }

    float t[ROWS_PER_WAVE], a[ROWS_PER_WAVE];
    #pragma unroll
    for (int r = 0; r < ROWS_PER_WAVE; ++r) {
        t[r] = MARGIN - gv[r];
        a[r] = 0.0f;
    }

    // a[r][lane] = sum_{c>lane} max(g_r[c] + t_r, 0); mask shared across rows.
    #pragma unroll
    for (int c = 1; c < NBEST; ++c) {
        float m01 = (lane < c) ? 1.0f : 0.0f;
        #pragma unroll
        for (int r = 0; r < ROWS_PER_WAVE; ++r) {
            float s = __uint_as_float(
                __builtin_amdgcn_readlane(__float_as_uint(gv[r]), c));
            a[r] += fmaxf(s + t[r], 0.0f) * m01;
        }
    }

    // Drop rows beyond B (no-op at B=16384), apply mean denominator.
    float accs = 0.0f;
    #pragma unroll
    for (int r = 0; r < ROWS_PER_WAVE; ++r)
        accs += (b0 + r < B) ? a[r] : 0.0f;
    int cnt = (NBEST - 1) - lane;                 // lane 63: acc==0 anyway
    float acc = accs / (float)(cnt > 0 ? cnt : 1);

    // Wave-64 shuffle reduction.
    #pragma unroll
    for (int off = 32; off > 0; off >>= 1)
        acc += __shfl_down(acc, off);

    __shared__ float wsum[4];
    if (lane == 0) wsum[wib] = acc;
    __syncthreads();
    if (threadIdx.x == 0)
        ws[blockIdx.x] = wsum[0] + wsum[1] + wsum[2] + wsum[3];
}

// Single-block reduction of per-block partials.
__global__ __launch_bounds__(256)
void sml_reduce(const float* __restrict__ ws, float* __restrict__ out, int n)
{
    const int lane = threadIdx.x & 63;
    const int wid  = threadIdx.x >> 6;
    float s = 0.0f;
    for (int i = threadIdx.x; i < n; i += 256) s += ws[i];
    #pragma unroll
    for (int off = 32; off > 0; off >>= 1)
        s += __shfl_down(s, off);
    __shared__ float wsum[4];
    if (lane == 0) wsum[wid] = s;
    __syncthreads();
    if (threadIdx.x == 0)
        out[0] = wsum[0] + wsum[1] + wsum[2] + wsum[3];
}

extern "C" void kernel_launch(void* const* d_in, const int* in_sizes, int n_in,
                              void* d_out, int out_size, void* d_ws, size_t ws_size,
                              hipStream_t stream)
{
    const float* scores    = (const float*)d_in[0];
    const unsigned int* wr = (const unsigned int*)d_in[1];
    const int B = in_sizes[0] / NBEST;

    const int rows_per_block = 4 * ROWS_PER_WAVE;            // 32
    const int blocks = (B + rows_per_block - 1) / rows_per_block;  // 512
    sml_kernel<<<blocks, 256, 0, stream>>>(scores, wr, (float*)d_ws, B);
    sml_reduce<<<1, 256, 0, stream>>>((const float*)d_ws, (float*)d_out, blocks);
}